// Round 7
// baseline (539.360 us; speedup 1.0000x reference)
//
#include <hip/hip_runtime.h>

using short8 = __attribute__((ext_vector_type(8))) short;
using f32x4  = __attribute__((ext_vector_type(4))) float;
using u16x4  = __attribute__((ext_vector_type(4))) unsigned short;
using fl4    = __attribute__((ext_vector_type(4))) float;

#define MFMA16(a, b, c) __builtin_amdgcn_mfma_f32_16x16x32_bf16((a), (b), (c), 0, 0, 0)

static __device__ __forceinline__ unsigned short f2bf(float f) {
  union { float f; unsigned u; } x; x.f = f;
  return (unsigned short)((x.u + 0x7FFFu + ((x.u >> 16) & 1u)) >> 16);
}
static __device__ __forceinline__ float bf2f(unsigned short s) {
  union { unsigned u; float f; } x; x.u = ((unsigned)s) << 16;
  return x.f;
}
// v_exp_f32 computes 2^x directly (input pre-scaled by log2e upstream)
static __device__ __forceinline__ float fexp2(float x) {
  float r; asm("v_exp_f32 %0, %1" : "=v"(r) : "v"(x)); return r;
}
// packed f32x2 -> bf16x2 (RNE), T12 recipe
static __device__ __forceinline__ unsigned pk2(float lo, float hi) {
  unsigned r; asm("v_cvt_pk_bf16_f32 %0, %1, %2" : "=v"(r) : "v"(lo), "v"(hi));
  return r;
}

// async global->LDS, 16B per lane; lds base must be wave-uniform.
static __device__ __forceinline__ void gload16(const void* g, void* l) {
  __builtin_amdgcn_global_load_lds((const __attribute__((address_space(1))) void*)g,
                                   (__attribute__((address_space(3))) void*)l, 16, 0, 0);
}

#define LOG2E 1.4426950408889634f

// ---------------------------------------------------------------------------
// Wt[n][k] = bf16(W[k][n]) for 4 weight matrices (z picks which)
// ---------------------------------------------------------------------------
__global__ __launch_bounds__(256) void k_wconv4(
    const float* __restrict__ W0, const float* __restrict__ W1,
    const float* __restrict__ W2, const float* __restrict__ W3,
    unsigned short* __restrict__ Wt0, unsigned short* __restrict__ Wt1,
    unsigned short* __restrict__ Wt2, unsigned short* __restrict__ Wt3) {
  const float* W = (blockIdx.z == 0) ? W0 : (blockIdx.z == 1) ? W1
                   : (blockIdx.z == 2) ? W2 : W3;
  unsigned short* Wt = (blockIdx.z == 0) ? Wt0 : (blockIdx.z == 1) ? Wt1
                       : (blockIdx.z == 2) ? Wt2 : Wt3;
  __shared__ float tile[64][65];
  const int t = threadIdx.x;
  const int n0 = blockIdx.x * 64, k0 = blockIdx.y * 64;
#pragma unroll
  for (int p = 0; p < 4; ++p) {
    int row = p * 16 + (t >> 4);
    int c4 = (t & 15) * 4;
    fl4 val = *(const fl4*)&W[(size_t)(k0 + row) * 1024 + n0 + c4];
    tile[row][c4 + 0] = val[0];
    tile[row][c4 + 1] = val[1];
    tile[row][c4 + 2] = val[2];
    tile[row][c4 + 3] = val[3];
  }
  __syncthreads();
#pragma unroll
  for (int p = 0; p < 4; ++p) {
    int n = p * 16 + (t >> 4);
    int k4 = (t & 15) * 4;
    u16x4 u;
    u[0] = f2bf(tile[k4 + 0][n]);
    u[1] = f2bf(tile[k4 + 1][n]);
    u[2] = f2bf(tile[k4 + 2][n]);
    u[3] = f2bf(tile[k4 + 3][n]);
    *(u16x4*)&Wt[(size_t)(n0 + n) * 1024 + k0 + k4] = u;
  }
}

// ---------------------------------------------------------------------------
// f32 -> bf16 bulk convert (q and v)
// ---------------------------------------------------------------------------
__global__ __launch_bounds__(256) void k_cvt(const float* __restrict__ a,
                                             const float* __restrict__ b,
                                             unsigned short* __restrict__ oa,
                                             unsigned short* __restrict__ ob) {
  const float* src = blockIdx.y ? b : a;
  unsigned short* dst = blockIdx.y ? ob : oa;
  size_t i = ((size_t)blockIdx.x * 256 + threadIdx.x) * 8;
  fl4 v0 = *(const fl4*)&src[i];
  fl4 v1 = *(const fl4*)&src[i + 4];
  u16x4 u0, u1;
  u0[0] = f2bf(v0[0]); u0[1] = f2bf(v0[1]); u0[2] = f2bf(v0[2]); u0[3] = f2bf(v0[3]);
  u1[0] = f2bf(v1[0]); u1[1] = f2bf(v1[1]); u1[2] = f2bf(v1[2]); u1[3] = f2bf(v1[3]);
  *(u16x4*)&dst[i] = u0;
  *(u16x4*)&dst[i + 4] = u1;
}

// ---------------------------------------------------------------------------
// 3-deep pipelined bf16 GEMM core (unchanged from r6; race-fixed counted-vmcnt)
// ---------------------------------------------------------------------------
#define GEMM3_CORE(APTR, BPTR)                                                  \
  const int t = threadIdx.x, lane = t & 63, w = t >> 6;                         \
  const int g = lane >> 4, ln = lane & 15;                                      \
  const int wm = w >> 1, wn = w & 1;                                            \
  __shared__ unsigned short sh[24576]; /* 3 bufs x (A 4096 + B 4096) elems */   \
  const int srow = lane >> 2;                                                   \
  const int sc = (lane & 3) ^ ((lane >> 3) & 3);                                \
  const int rsw = ((ln >> 1) & 3);                                              \
  f32x4 acc[4][4] = {};                                                         \
  _Pragma("unroll") for (int pre = 0; pre < 2; ++pre) {                         \
    _Pragma("unroll") for (int p = 0; p < 2; ++p) {                             \
      gload16(&APTR[(size_t)(m0 + p * 64 + w * 16 + srow) * 1024 + pre * 32 + sc * 8], \
              &sh[pre * 8192 + (p * 64 + w * 16) * 32]);                        \
      gload16(&BPTR[(size_t)(n0 + p * 64 + w * 16 + srow) * 1024 + pre * 32 + sc * 8], \
              &sh[pre * 8192 + 4096 + (p * 64 + w * 16) * 32]);                 \
    }                                                                           \
  }                                                                             \
  int cur = 0;                                                                  \
  for (int tt = 0; tt < 32; ++tt) {                                             \
    if (tt < 31) {                                                              \
      asm volatile("s_waitcnt vmcnt(4)" ::: "memory");                          \
    } else {                                                                    \
      asm volatile("s_waitcnt vmcnt(0)" ::: "memory");                          \
    }                                                                           \
    __builtin_amdgcn_sched_barrier(0);                                          \
    __builtin_amdgcn_s_barrier();                                               \
    __builtin_amdgcn_sched_barrier(0);                                          \
    if (tt < 30) {                                                              \
      int bb = cur + 2; if (bb >= 3) bb -= 3;                                   \
      int kk = (tt + 2) * 32;                                                   \
      _Pragma("unroll") for (int p = 0; p < 2; ++p) {                           \
        gload16(&APTR[(size_t)(m0 + p * 64 + w * 16 + srow) * 1024 + kk + sc * 8], \
                &sh[bb * 8192 + (p * 64 + w * 16) * 32]);                       \
        gload16(&BPTR[(size_t)(n0 + p * 64 + w * 16 + srow) * 1024 + kk + sc * 8], \
                &sh[bb * 8192 + 4096 + (p * 64 + w * 16) * 32]);                \
      }                                                                         \
    }                                                                           \
    const unsigned short* As = &sh[cur * 8192];                                 \
    const unsigned short* Bs = As + 4096;                                       \
    short8 af[4], bfr[4];                                                       \
    _Pragma("unroll") for (int fm = 0; fm < 4; ++fm)                            \
        af[fm] = *(const short8*)&As[(wm * 64 + fm * 16 + ln) * 32 + (g ^ rsw) * 8]; \
    _Pragma("unroll") for (int fn = 0; fn < 4; ++fn)                            \
        bfr[fn] = *(const short8*)&Bs[(wn * 64 + fn * 16 + ln) * 32 + (g ^ rsw) * 8]; \
    _Pragma("unroll") for (int fn = 0; fn < 4; ++fn) {                          \
      _Pragma("unroll") for (int fm = 0; fm < 4; ++fm)                          \
          acc[fm][fn] = MFMA16(af[fm], bfr[fn], acc[fm][fn]);                   \
    }                                                                           \
    cur = (cur == 2) ? 0 : cur + 1;                                             \
  }

// ---------------------------------------------------------------------------
// Projections (pipelined): mode 0=QW (scaled log2e/8), 1=KW, 2=VWT
// ---------------------------------------------------------------------------
__global__ __launch_bounds__(256) void k_proj3(
    const unsigned short* __restrict__ QB, const unsigned short* __restrict__ VB,
    const unsigned short* __restrict__ WtQ, const unsigned short* __restrict__ WtK,
    const unsigned short* __restrict__ WtV,
    const float* __restrict__ bq, const float* __restrict__ bk,
    const float* __restrict__ bv,
    unsigned short* __restrict__ QW, unsigned short* __restrict__ KW,
    unsigned short* __restrict__ VWT) {
  const int mode = blockIdx.z;
  const unsigned short* A8 = (mode == 0) ? QB : VB;
  const unsigned short* Wt = (mode == 0) ? WtQ : (mode == 1) ? WtK : WtV;
  const float* bias = (mode == 0) ? bq : (mode == 1) ? bk : bv;
  const int n0 = blockIdx.x * 128, m0 = blockIdx.y * 128;
  GEMM3_CORE(A8, Wt)
  __syncthreads();
  const float scale = (mode == 0) ? (0.125f * LOG2E) : 1.0f;
#pragma unroll
  for (int fn = 0; fn < 4; ++fn) {
    float bn = bias[n0 + wn * 64 + fn * 16 + ln];
#pragma unroll
    for (int fm = 0; fm < 4; ++fm) {
#pragma unroll
      for (int r = 0; r < 4; ++r) {
        float val = (acc[fm][fn][r] + bn) * scale;
        sh[(wm * 64 + fm * 16 + 4 * g + r) * 132 + wn * 64 + fn * 16 + ln] = f2bf(val);
      }
    }
  }
  __syncthreads();
  if (mode < 2) {
    unsigned short* OUT = (mode == 0) ? QW : KW;
#pragma unroll
    for (int p = 0; p < 16; ++p) {
      int row = p * 8 + (t >> 5), c4 = (t & 31) * 4;
      *(u16x4*)&OUT[(size_t)(m0 + row) * 1024 + n0 + c4] =
          *(const u16x4*)&sh[row * 132 + c4];
    }
  } else {
    const int b = m0 >> 10, s0 = m0 & 1023;
#pragma unroll
    for (int p = 0; p < 16; ++p) {
#pragma unroll
      for (int qh = 0; qh < 2; ++qh) {
        int hdl = p * 8 + (t >> 5);
        int sl = qh * 64 + (t & 31) * 2;
        unsigned lo = sh[sl * 132 + hdl];
        unsigned hi = sh[(sl + 1) * 132 + hdl];
        int hd = n0 + hdl;
        int h = hd >> 6, d = hd & 63;
        *(unsigned*)&VWT[((size_t)(b * 16 + h) * 64 + d) * 1024 + s0 + sl] =
            lo | (hi << 16);
      }
    }
  }
}

// ---------------------------------------------------------------------------
// Output projection (pipelined): out = (OB @ Wo + bo) * q_mask  (f32 out)
// ---------------------------------------------------------------------------
__global__ __launch_bounds__(256) void k_out3(
    const unsigned short* __restrict__ OB, const unsigned short* __restrict__ WtO,
    const float* __restrict__ bo, const int* __restrict__ qmask,
    float* __restrict__ out) {
  const int n0 = blockIdx.x * 128, m0 = blockIdx.y * 128;
  GEMM3_CORE(OB, WtO)
  float bn[4];
#pragma unroll
  for (int fn = 0; fn < 4; ++fn) bn[fn] = bo[n0 + wn * 64 + fn * 16 + ln];
#pragma unroll
  for (int fm = 0; fm < 4; ++fm) {
#pragma unroll
    for (int r = 0; r < 4; ++r) {
      int row = m0 + wm * 64 + fm * 16 + 4 * g + r;
      float qm = (float)qmask[row];
#pragma unroll
      for (int fn = 0; fn < 4; ++fn)
        out[(size_t)row * 1024 + n0 + wn * 64 + fn * 16 + ln] =
            (acc[fm][fn][r] + bn[fn]) * qm;
    }
  }
}

// ---------------------------------------------------------------------------
// Position-bias scores, stripe of 512 j: CB[bh][jl 512][k 1024]
// Key mask (-NEG*log2e for masked keys) folded into CB here.
// ---------------------------------------------------------------------------
__global__ __launch_bounds__(256) void k_pbias(
    const unsigned short* __restrict__ QW, const float* __restrict__ pb,
    const int* __restrict__ vmask, unsigned short* __restrict__ CB, int jbase) {
  const int kt = blockIdx.x;  // 0..7
  const int jl = blockIdx.y;  // 0..511
  const int j = jbase + jl;
  const int t = threadIdx.x, lane = t & 63, w = t >> 6;
  const int g = lane >> 4, ln = lane & 15;
  const int wm = w >> 1, wn = w & 1;
  __shared__ unsigned short sm[18432];
  unsigned short* a_lds = sm;         // [128 bh][72]
  unsigned short* b_lds = sm + 9216;  // [128 k][72]
#pragma unroll
  for (int p = 0; p < 8; ++p) {
    int i4 = p * 256 + t;
    int row = i4 >> 4, c4 = (i4 & 15) * 4;
    *(u16x4*)&a_lds[row * 72 + c4] =
        *(const u16x4*)&QW[((size_t)(row >> 4) * 1024 + j) * 1024 + (row & 15) * 64 + c4];
  }
#pragma unroll
  for (int p = 0; p < 8; ++p) {
    int i4 = p * 256 + t;
    int row = i4 >> 4, c4 = (i4 & 15) * 4;
    fl4 val = *(const fl4*)&pb[((size_t)j * 1024 + kt * 128 + row) * 64 + c4];
    u16x4 u;
    u[0] = f2bf(val[0]); u[1] = f2bf(val[1]);
    u[2] = f2bf(val[2]); u[3] = f2bf(val[3]);
    *(u16x4*)&b_lds[row * 72 + c4] = u;
  }
  __syncthreads();
  f32x4 acc[4][4] = {};
#pragma unroll
  for (int ks = 0; ks < 2; ++ks) {
    short8 af[4];
#pragma unroll
    for (int fm = 0; fm < 4; ++fm)
      af[fm] = *(const short8*)&a_lds[(wm * 64 + fm * 16 + ln) * 72 + ks * 32 + 8 * g];
#pragma unroll
    for (int fn = 0; fn < 4; ++fn) {
      short8 bfr = *(const short8*)&b_lds[(wn * 64 + fn * 16 + ln) * 72 + ks * 32 + 8 * g];
#pragma unroll
      for (int fm = 0; fm < 4; ++fm) acc[fm][fn] = MFMA16(af[fm], bfr, acc[fm][fn]);
    }
  }
  __syncthreads();
#pragma unroll
  for (int fn = 0; fn < 4; ++fn) {
    int kcol = kt * 128 + wn * 64 + fn * 16 + ln;
#pragma unroll
    for (int fm = 0; fm < 4; ++fm) {
      // b of output row (bh = wm*64+fm*16+4g+r): b = bh>>4 = wm*4+fm
      float off = vmask[(wm * 4 + fm) * 1024 + kcol] ? 0.f : (-1e12f * LOG2E);
#pragma unroll
      for (int r = 0; r < 4; ++r)
        sm[(wm * 64 + fm * 16 + 4 * g + r) * 132 + wn * 64 + fn * 16 + ln] =
            f2bf(acc[fm][fn][r] + off);
    }
  }
  __syncthreads();
#pragma unroll
  for (int p = 0; p < 16; ++p) {
    int row = p * 8 + (t >> 5), c4 = (t & 31) * 4;
    *(u16x4*)&CB[((size_t)row * 512 + jl) * 1024 + kt * 128 + c4] =
        *(const u16x4*)&sm[row * 132 + c4];
  }
}

// ---------------------------------------------------------------------------
// Flash attention, swapped-operand, GLOBAL-DIRECT K/V (lesson #7: K,V slabs are
// 128KB/head = L2-resident; LDS staging was pure overhead). No barriers in the
// kt loop (only per-wave P region in LDS). 4 blocks/CU via launch_bounds.
// ---------------------------------------------------------------------------
__global__ __launch_bounds__(256, 4) void k_attn(
    const unsigned short* __restrict__ QW, const unsigned short* __restrict__ KW,
    const unsigned short* __restrict__ VWT, const unsigned short* __restrict__ CB,
    unsigned short* __restrict__ OB, int jbase) {
  const int jt = blockIdx.x, h = blockIdx.y, b = blockIdx.z;
  const int t = threadIdx.x, lane = t & 63, w = t >> 6;
  const int g = lane >> 4, ln = lane & 15;
  const int j0 = jbase + jt * 64;
  const int jl0 = jt * 64;
  __shared__ unsigned short lds_p[4 * 16 * 136];
  unsigned short* pw = &lds_p[w * (16 * 136)];
  short8 qf[2];
  {
    const size_t qrow = ((size_t)b * 1024 + (j0 + w * 16 + ln)) * 1024 + h * 64;
    qf[0] = *(const short8*)&QW[qrow + 8 * g];
    qf[1] = *(const short8*)&QW[qrow + 32 + 8 * g];
  }
  const size_t cb_row = ((size_t)(b * 16 + h) * 512 + jl0 + w * 16 + ln) * 1024;
  const unsigned short* Kb = &KW[(size_t)b * 1024 * 1024 + h * 64];        // row k, col d
  const unsigned short* Vb = &VWT[((size_t)(b * 16 + h) * 64) * 1024];     // row d, col k

  f32x4 o_acc[4] = {};
  float l_par = 0.f;

  for (int kt = 0; kt < 8; ++kt) {
    // S^T init from CB (C-layout: row k = fm*16+4g+r, col j = ln)
    f32x4 s[8];
#pragma unroll
    for (int fm = 0; fm < 8; ++fm) {
      u16x4 c = *(const u16x4*)&CB[cb_row + kt * 128 + fm * 16 + 4 * g];
#pragma unroll
      for (int r = 0; r < 4; ++r) s[fm][r] = bf2f(c[r]);
    }
    // S^T += K x Q  (A-fragments straight from global; 16 rows x 64B per load, coalesced)
#pragma unroll
    for (int ks = 0; ks < 2; ++ks) {
#pragma unroll
      for (int fm = 0; fm < 8; ++fm) {
        short8 af = *(const short8*)&Kb[(size_t)(kt * 128 + fm * 16 + ln) * 1024 +
                                        ks * 32 + 8 * g];
        s[fm] = MFMA16(af, qf[ks], s[fm]);
      }
    }
    // P = 2^(s - 17)  (fixed shift; exact softmax after normalization)
#pragma unroll
    for (int fm = 0; fm < 8; ++fm) {
      float pv0 = fexp2(s[fm][0] - 17.0f);
      float pv1 = fexp2(s[fm][1] - 17.0f);
      float pv2 = fexp2(s[fm][2] - 17.0f);
      float pv3 = fexp2(s[fm][3] - 17.0f);
      l_par += (pv0 + pv1) + (pv2 + pv3);
      union { u16x4 v; unsigned u[2]; } pp;
      pp.u[0] = pk2(pv0, pv1);
      pp.u[1] = pk2(pv2, pv3);
      *(u16x4*)&pw[ln * 136 + fm * 16 + 4 * g] = pp.v;  // P^T -> [j=ln][k]
    }
    asm volatile("s_waitcnt lgkmcnt(0)" ::: "memory");
    __builtin_amdgcn_sched_barrier(0);
    // O^T += V^T x P^T  (V-fragments straight from global)
#pragma unroll
    for (int ks = 0; ks < 4; ++ks) {
      short8 bp = *(const short8*)&pw[ln * 136 + ks * 32 + 8 * g];
#pragma unroll
      for (int fm = 0; fm < 4; ++fm) {
        short8 av = *(const short8*)&Vb[(size_t)(fm * 16 + ln) * 1024 +
                                        kt * 128 + ks * 32 + 8 * g];
        o_acc[fm] = MFMA16(av, bp, o_acc[fm]);
      }
    }
  }
  // row-sum: lanes with same ln (xor 16, 32) hold the 4 k-quarters of row j
  l_par += __shfl_xor(l_par, 16);
  l_par += __shfl_xor(l_par, 32);
  float inv = 1.0f / l_par;
  const size_t orow = ((size_t)b * 1024 + (j0 + w * 16 + ln)) * 1024 + h * 64;
#pragma unroll
  for (int fm = 0; fm < 4; ++fm) {
    union { u16x4 v; unsigned u[2]; } uo;
    uo.u[0] = pk2(o_acc[fm][0] * inv, o_acc[fm][1] * inv);
    uo.u[1] = pk2(o_acc[fm][2] * inv, o_acc[fm][3] * inv);
    *(u16x4*)&OB[orow + fm * 16 + 4 * g] = uo.v;  // d = fm*16+4g+r
  }
}

// ---------------------------------------------------------------------------
extern "C" void kernel_launch(void* const* d_in, const int* in_sizes, int n_in,
                              void* d_out, int out_size, void* d_ws, size_t ws_size,
                              hipStream_t stream) {
  const float* q  = (const float*)d_in[0];
  // d_in[1] = k  -- intentionally unused (reference projects K from v)
  const float* v  = (const float*)d_in[2];
  const float* pb = (const float*)d_in[3];
  const float* Wq = (const float*)d_in[4];
  const float* Wk = (const float*)d_in[5];
  const float* Wv = (const float*)d_in[6];
  const float* Wo = (const float*)d_in[7];
  const float* bq = (const float*)d_in[8];
  const float* bk = (const float*)d_in[9];
  const float* bv = (const float*)d_in[10];
  const float* bo = (const float*)d_in[11];
  const int* qm = (const int*)d_in[12];
  const int* vm = (const int*)d_in[13];
  float* out = (float*)d_out;

  unsigned short* ws = (unsigned short*)d_ws;
  const size_t M1 = 1024 * 1024;
  unsigned short* WTQ = ws;
  unsigned short* WTK = WTQ + M1;
  unsigned short* WTV = WTK + M1;
  unsigned short* WTO = WTV + M1;
  unsigned short* QB  = WTO + M1;              // [8192][1024] bf16(q)
  unsigned short* VB  = QB + 8 * M1;           // [8192][1024] bf16(v)
  unsigned short* QW  = VB + 8 * M1;           // [8192][1024], scaled log2e/8
  unsigned short* KW  = QW + 8 * M1;
  unsigned short* VWT = KW + 8 * M1;           // [b][h][d][s]
  unsigned short* OB  = VWT + 8 * M1;
  unsigned short* CB  = OB + 8 * M1;           // [bh 128][jl 512][k 1024] stripe (134MB)

  k_wconv4<<<dim3(16, 16, 4), 256, 0, stream>>>(Wq, Wk, Wv, Wo, WTQ, WTK, WTV, WTO);
  k_cvt<<<dim3(4096, 2), 256, 0, stream>>>(q, v, QB, VB);
  k_proj3<<<dim3(8, 64, 3), 256, 0, stream>>>(QB, VB, WTQ, WTK, WTV, bq, bk, bv,
                                              QW, KW, VWT);
  for (int st = 0; st < 2; ++st) {
    k_pbias<<<dim3(8, 512), 256, 0, stream>>>(QW, pb, vm, CB, st * 512);
    k_attn<<<dim3(8, 16, 8), 256, 0, stream>>>(QW, KW, VWT, CB, OB, st * 512);
  }
  k_out3<<<dim3(8, 64), 256, 0, stream>>>(OB, WTO, bo, qm, out);
}

// Round 8
// 377.577 us; speedup vs baseline: 1.4285x; 1.4285x over previous
//
#include <hip/hip_runtime.h>

using short8 = __attribute__((ext_vector_type(8))) short;
using f32x4  = __attribute__((ext_vector_type(4))) float;
using u16x4  = __attribute__((ext_vector_type(4))) unsigned short;
using fl4    = __attribute__((ext_vector_type(4))) float;

#define MFMA16(a, b, c) __builtin_amdgcn_mfma_f32_16x16x32_bf16((a), (b), (c), 0, 0, 0)

static __device__ __forceinline__ unsigned short f2bf(float f) {
  union { float f; unsigned u; } x; x.f = f;
  return (unsigned short)((x.u + 0x7FFFu + ((x.u >> 16) & 1u)) >> 16);
}
static __device__ __forceinline__ float bf2f(unsigned short s) {
  union { unsigned u; float f; } x; x.u = ((unsigned)s) << 16;
  return x.f;
}
// v_exp_f32 computes 2^x directly (input pre-scaled by log2e upstream)
static __device__ __forceinline__ float fexp2(float x) {
  float r; asm("v_exp_f32 %0, %1" : "=v"(r) : "v"(x)); return r;
}
// packed f32x2 -> bf16x2 (RNE), T12 recipe
static __device__ __forceinline__ unsigned pk2(float lo, float hi) {
  unsigned r; asm("v_cvt_pk_bf16_f32 %0, %1, %2" : "=v"(r) : "v"(lo), "v"(hi));
  return r;
}

// async global->LDS, 16B per lane; lds base must be wave-uniform.
static __device__ __forceinline__ void gload16(const void* g, void* l) {
  __builtin_amdgcn_global_load_lds((const __attribute__((address_space(1))) void*)g,
                                   (__attribute__((address_space(3))) void*)l, 16, 0, 0);
}

#define LOG2E 1.4426950408889634f

// ---------------------------------------------------------------------------
// Wt[n][k] = bf16(W[k][n]) for 4 weight matrices (z picks which)
// ---------------------------------------------------------------------------
__global__ __launch_bounds__(256) void k_wconv4(
    const float* __restrict__ W0, const float* __restrict__ W1,
    const float* __restrict__ W2, const float* __restrict__ W3,
    unsigned short* __restrict__ Wt0, unsigned short* __restrict__ Wt1,
    unsigned short* __restrict__ Wt2, unsigned short* __restrict__ Wt3) {
  const float* W = (blockIdx.z == 0) ? W0 : (blockIdx.z == 1) ? W1
                   : (blockIdx.z == 2) ? W2 : W3;
  unsigned short* Wt = (blockIdx.z == 0) ? Wt0 : (blockIdx.z == 1) ? Wt1
                       : (blockIdx.z == 2) ? Wt2 : Wt3;
  __shared__ float tile[64][65];
  const int t = threadIdx.x;
  const int n0 = blockIdx.x * 64, k0 = blockIdx.y * 64;
#pragma unroll
  for (int p = 0; p < 4; ++p) {
    int row = p * 16 + (t >> 4);
    int c4 = (t & 15) * 4;
    fl4 val = *(const fl4*)&W[(size_t)(k0 + row) * 1024 + n0 + c4];
    tile[row][c4 + 0] = val[0];
    tile[row][c4 + 1] = val[1];
    tile[row][c4 + 2] = val[2];
    tile[row][c4 + 3] = val[3];
  }
  __syncthreads();
#pragma unroll
  for (int p = 0; p < 4; ++p) {
    int n = p * 16 + (t >> 4);
    int k4 = (t & 15) * 4;
    u16x4 u;
    u[0] = f2bf(tile[k4 + 0][n]);
    u[1] = f2bf(tile[k4 + 1][n]);
    u[2] = f2bf(tile[k4 + 2][n]);
    u[3] = f2bf(tile[k4 + 3][n]);
    *(u16x4*)&Wt[(size_t)(n0 + n) * 1024 + k0 + k4] = u;
  }
}

// ---------------------------------------------------------------------------
// f32 -> bf16 bulk convert (q and v)
// ---------------------------------------------------------------------------
__global__ __launch_bounds__(256) void k_cvt(const float* __restrict__ a,
                                             const float* __restrict__ b,
                                             unsigned short* __restrict__ oa,
                                             unsigned short* __restrict__ ob) {
  const float* src = blockIdx.y ? b : a;
  unsigned short* dst = blockIdx.y ? ob : oa;
  size_t i = ((size_t)blockIdx.x * 256 + threadIdx.x) * 8;
  fl4 v0 = *(const fl4*)&src[i];
  fl4 v1 = *(const fl4*)&src[i + 4];
  u16x4 u0, u1;
  u0[0] = f2bf(v0[0]); u0[1] = f2bf(v0[1]); u0[2] = f2bf(v0[2]); u0[3] = f2bf(v0[3]);
  u1[0] = f2bf(v1[0]); u1[1] = f2bf(v1[1]); u1[2] = f2bf(v1[2]); u1[3] = f2bf(v1[3]);
  *(u16x4*)&dst[i] = u0;
  *(u16x4*)&dst[i + 4] = u1;
}

// ---------------------------------------------------------------------------
// 3-deep pipelined bf16 GEMM core (race-fixed counted-vmcnt, unchanged)
// ---------------------------------------------------------------------------
#define GEMM3_CORE(APTR, BPTR)                                                  \
  const int t = threadIdx.x, lane = t & 63, w = t >> 6;                         \
  const int g = lane >> 4, ln = lane & 15;                                      \
  const int wm = w >> 1, wn = w & 1;                                            \
  __shared__ unsigned short sh[24576]; /* 3 bufs x (A 4096 + B 4096) elems */   \
  const int srow = lane >> 2;                                                   \
  const int sc = (lane & 3) ^ ((lane >> 3) & 3);                                \
  const int rsw = ((ln >> 1) & 3);                                              \
  f32x4 acc[4][4] = {};                                                         \
  _Pragma("unroll") for (int pre = 0; pre < 2; ++pre) {                         \
    _Pragma("unroll") for (int p = 0; p < 2; ++p) {                             \
      gload16(&APTR[(size_t)(m0 + p * 64 + w * 16 + srow) * 1024 + pre * 32 + sc * 8], \
              &sh[pre * 8192 + (p * 64 + w * 16) * 32]);                        \
      gload16(&BPTR[(size_t)(n0 + p * 64 + w * 16 + srow) * 1024 + pre * 32 + sc * 8], \
              &sh[pre * 8192 + 4096 + (p * 64 + w * 16) * 32]);                 \
    }                                                                           \
  }                                                                             \
  int cur = 0;                                                                  \
  for (int tt = 0; tt < 32; ++tt) {                                             \
    if (tt < 31) {                                                              \
      asm volatile("s_waitcnt vmcnt(4)" ::: "memory");                          \
    } else {                                                                    \
      asm volatile("s_waitcnt vmcnt(0)" ::: "memory");                          \
    }                                                                           \
    __builtin_amdgcn_sched_barrier(0);                                          \
    __builtin_amdgcn_s_barrier();                                               \
    __builtin_amdgcn_sched_barrier(0);                                          \
    if (tt < 30) {                                                              \
      int bb = cur + 2; if (bb >= 3) bb -= 3;                                   \
      int kk = (tt + 2) * 32;                                                   \
      _Pragma("unroll") for (int p = 0; p < 2; ++p) {                           \
        gload16(&APTR[(size_t)(m0 + p * 64 + w * 16 + srow) * 1024 + kk + sc * 8], \
                &sh[bb * 8192 + (p * 64 + w * 16) * 32]);                       \
        gload16(&BPTR[(size_t)(n0 + p * 64 + w * 16 + srow) * 1024 + kk + sc * 8], \
                &sh[bb * 8192 + 4096 + (p * 64 + w * 16) * 32]);                \
      }                                                                         \
    }                                                                           \
    const unsigned short* As = &sh[cur * 8192];                                 \
    const unsigned short* Bs = As + 4096;                                       \
    short8 af[4], bfr[4];                                                       \
    _Pragma("unroll") for (int fm = 0; fm < 4; ++fm)                            \
        af[fm] = *(const short8*)&As[(wm * 64 + fm * 16 + ln) * 32 + (g ^ rsw) * 8]; \
    _Pragma("unroll") for (int fn = 0; fn < 4; ++fn)                            \
        bfr[fn] = *(const short8*)&Bs[(wn * 64 + fn * 16 + ln) * 32 + (g ^ rsw) * 8]; \
    _Pragma("unroll") for (int fn = 0; fn < 4; ++fn) {                          \
      _Pragma("unroll") for (int fm = 0; fm < 4; ++fm)                          \
          acc[fm][fn] = MFMA16(af[fm], bfr[fn], acc[fm][fn]);                   \
    }                                                                           \
    cur = (cur == 2) ? 0 : cur + 1;                                             \
  }

// ---------------------------------------------------------------------------
// Projections (pipelined): mode 0=QW (scaled log2e/8), 1=KW, 2=VWT
// ---------------------------------------------------------------------------
__global__ __launch_bounds__(256) void k_proj3(
    const unsigned short* __restrict__ QB, const unsigned short* __restrict__ VB,
    const unsigned short* __restrict__ WtQ, const unsigned short* __restrict__ WtK,
    const unsigned short* __restrict__ WtV,
    const float* __restrict__ bq, const float* __restrict__ bk,
    const float* __restrict__ bv,
    unsigned short* __restrict__ QW, unsigned short* __restrict__ KW,
    unsigned short* __restrict__ VWT) {
  const int mode = blockIdx.z;
  const unsigned short* A8 = (mode == 0) ? QB : VB;
  const unsigned short* Wt = (mode == 0) ? WtQ : (mode == 1) ? WtK : WtV;
  const float* bias = (mode == 0) ? bq : (mode == 1) ? bk : bv;
  const int n0 = blockIdx.x * 128, m0 = blockIdx.y * 128;
  GEMM3_CORE(A8, Wt)
  __syncthreads();
  const float scale = (mode == 0) ? (0.125f * LOG2E) : 1.0f;
#pragma unroll
  for (int fn = 0; fn < 4; ++fn) {
    float bn = bias[n0 + wn * 64 + fn * 16 + ln];
#pragma unroll
    for (int fm = 0; fm < 4; ++fm) {
#pragma unroll
      for (int r = 0; r < 4; ++r) {
        float val = (acc[fm][fn][r] + bn) * scale;
        sh[(wm * 64 + fm * 16 + 4 * g + r) * 132 + wn * 64 + fn * 16 + ln] = f2bf(val);
      }
    }
  }
  __syncthreads();
  if (mode < 2) {
    unsigned short* OUT = (mode == 0) ? QW : KW;
#pragma unroll
    for (int p = 0; p < 16; ++p) {
      int row = p * 8 + (t >> 5), c4 = (t & 31) * 4;
      *(u16x4*)&OUT[(size_t)(m0 + row) * 1024 + n0 + c4] =
          *(const u16x4*)&sh[row * 132 + c4];
    }
  } else {
    const int b = m0 >> 10, s0 = m0 & 1023;
#pragma unroll
    for (int p = 0; p < 16; ++p) {
#pragma unroll
      for (int qh = 0; qh < 2; ++qh) {
        int hdl = p * 8 + (t >> 5);
        int sl = qh * 64 + (t & 31) * 2;
        unsigned lo = sh[sl * 132 + hdl];
        unsigned hi = sh[(sl + 1) * 132 + hdl];
        int hd = n0 + hdl;
        int h = hd >> 6, d = hd & 63;
        *(unsigned*)&VWT[((size_t)(b * 16 + h) * 64 + d) * 1024 + s0 + sl] =
            lo | (hi << 16);
      }
    }
  }
}

// ---------------------------------------------------------------------------
// Output projection (pipelined): out = (OB @ Wo + bo) * q_mask  (f32 out)
// ---------------------------------------------------------------------------
__global__ __launch_bounds__(256) void k_out3(
    const unsigned short* __restrict__ OB, const unsigned short* __restrict__ WtO,
    const float* __restrict__ bo, const int* __restrict__ qmask,
    float* __restrict__ out) {
  const int n0 = blockIdx.x * 128, m0 = blockIdx.y * 128;
  GEMM3_CORE(OB, WtO)
  float bn[4];
#pragma unroll
  for (int fn = 0; fn < 4; ++fn) bn[fn] = bo[n0 + wn * 64 + fn * 16 + ln];
#pragma unroll
  for (int fm = 0; fm < 4; ++fm) {
#pragma unroll
    for (int r = 0; r < 4; ++r) {
      int row = m0 + wm * 64 + fm * 16 + 4 * g + r;
      float qm = (float)qmask[row];
#pragma unroll
      for (int fn = 0; fn < 4; ++fn)
        out[(size_t)row * 1024 + n0 + wn * 64 + fn * 16 + ln] =
            (acc[fm][fn][r] + bn[fn]) * qm;
    }
  }
}

// ---------------------------------------------------------------------------
// Position-bias scores, stripe of 512 j: CB[bh][jl 512][k 1024]
// Key mask (-NEG*log2e for masked keys) folded into CB here.
// ---------------------------------------------------------------------------
__global__ __launch_bounds__(256) void k_pbias(
    const unsigned short* __restrict__ QW, const float* __restrict__ pb,
    const int* __restrict__ vmask, unsigned short* __restrict__ CB, int jbase) {
  const int kt = blockIdx.x;  // 0..7
  const int jl = blockIdx.y;  // 0..511
  const int j = jbase + jl;
  const int t = threadIdx.x, lane = t & 63, w = t >> 6;
  const int g = lane >> 4, ln = lane & 15;
  const int wm = w >> 1, wn = w & 1;
  __shared__ unsigned short sm[18432];
  unsigned short* a_lds = sm;         // [128 bh][72]
  unsigned short* b_lds = sm + 9216;  // [128 k][72]
#pragma unroll
  for (int p = 0; p < 8; ++p) {
    int i4 = p * 256 + t;
    int row = i4 >> 4, c4 = (i4 & 15) * 4;
    *(u16x4*)&a_lds[row * 72 + c4] =
        *(const u16x4*)&QW[((size_t)(row >> 4) * 1024 + j) * 1024 + (row & 15) * 64 + c4];
  }
#pragma unroll
  for (int p = 0; p < 8; ++p) {
    int i4 = p * 256 + t;
    int row = i4 >> 4, c4 = (i4 & 15) * 4;
    fl4 val = *(const fl4*)&pb[((size_t)j * 1024 + kt * 128 + row) * 64 + c4];
    u16x4 u;
    u[0] = f2bf(val[0]); u[1] = f2bf(val[1]);
    u[2] = f2bf(val[2]); u[3] = f2bf(val[3]);
    *(u16x4*)&b_lds[row * 72 + c4] = u;
  }
  __syncthreads();
  f32x4 acc[4][4] = {};
#pragma unroll
  for (int ks = 0; ks < 2; ++ks) {
    short8 af[4];
#pragma unroll
    for (int fm = 0; fm < 4; ++fm)
      af[fm] = *(const short8*)&a_lds[(wm * 64 + fm * 16 + ln) * 72 + ks * 32 + 8 * g];
#pragma unroll
    for (int fn = 0; fn < 4; ++fn) {
      short8 bfr = *(const short8*)&b_lds[(wn * 64 + fn * 16 + ln) * 72 + ks * 32 + 8 * g];
#pragma unroll
      for (int fm = 0; fm < 4; ++fm) acc[fm][fn] = MFMA16(af[fm], bfr, acc[fm][fn]);
    }
  }
  __syncthreads();
#pragma unroll
  for (int fn = 0; fn < 4; ++fn) {
    int kcol = kt * 128 + wn * 64 + fn * 16 + ln;
#pragma unroll
    for (int fm = 0; fm < 4; ++fm) {
      // b of output row (bh = wm*64+fm*16+4g+r): b = bh>>4 = wm*4+fm
      float off = vmask[(wm * 4 + fm) * 1024 + kcol] ? 0.f : (-1e12f * LOG2E);
#pragma unroll
      for (int r = 0; r < 4; ++r)
        sm[(wm * 64 + fm * 16 + 4 * g + r) * 132 + wn * 64 + fn * 16 + ln] =
            f2bf(acc[fm][fn][r] + off);
    }
  }
  __syncthreads();
#pragma unroll
  for (int p = 0; p < 16; ++p) {
    int row = p * 8 + (t >> 5), c4 = (t & 31) * 4;
    *(u16x4*)&CB[((size_t)row * 512 + jl) * 1024 + kt * 128 + c4] =
        *(const u16x4*)&sm[row * 132 + c4];
  }
}

// ---------------------------------------------------------------------------
// Flash attention (R6 structure restored): swapped-operand, LDS-staged K/V with
// register prefetch (T14). NEW: XCD-locality swizzle — the 8 jt-blocks of one
// (b,h) map to the SAME XCD so K/V L2 lines are shared (1 fill vs 8).
// Grid: 1D 1024 blocks per stripe.
// ---------------------------------------------------------------------------
__global__ __launch_bounds__(256) void k_attn(
    const unsigned short* __restrict__ QW, const unsigned short* __restrict__ KW,
    const unsigned short* __restrict__ VWT, const unsigned short* __restrict__ CB,
    unsigned short* __restrict__ OB, int jbase) {
  // XCD swizzle: hw id B -> work w = (B%8)*128 + B/8  (bijective, 1024 blocks)
  const int B = blockIdx.x;
  const int wrk = (B & 7) * 128 + (B >> 3);
  const int jt = wrk & 7, h = (wrk >> 3) & 15, b = wrk >> 7;
  const int t = threadIdx.x, lane = t & 63, w = t >> 6;
  const int g = lane >> 4, ln = lane & 15;
  const int j0 = jbase + jt * 64;
  const int jl0 = jt * 64;
  __shared__ unsigned short lds_k[128 * 72];   // [k 128][d 72]
  __shared__ unsigned short lds_vt[64 * 136];  // [d 64][k 136]
  __shared__ unsigned short lds_p[4 * 16 * 136];
  unsigned short* pw = &lds_p[w * (16 * 136)];
  short8 qf[2];
  {
    const size_t qrow = ((size_t)b * 1024 + (j0 + w * 16 + ln)) * 1024 + h * 64;
    qf[0] = *(const short8*)&QW[qrow + 8 * g];
    qf[1] = *(const short8*)&QW[qrow + 32 + 8 * g];
  }
  const size_t cb_row = ((size_t)(b * 16 + h) * 512 + jl0 + w * 16 + ln) * 1024;

  u16x4 rk[8], rv[8], rcb[8];
#define LOAD_KV(kt_)                                                              \
  {                                                                               \
    _Pragma("unroll") for (int p = 0; p < 8; ++p) {                               \
      int i4 = p * 256 + t;                                                       \
      int row = i4 >> 4, c4 = (i4 & 15) * 4;                                      \
      rk[p] = *(const u16x4*)&KW[((size_t)b * 1024 + (kt_) * 128 + row) * 1024 +  \
                                 h * 64 + c4];                                    \
    }                                                                             \
    _Pragma("unroll") for (int p = 0; p < 8; ++p) {                               \
      int i4 = p * 256 + t;                                                       \
      int row = i4 >> 5, c4 = (i4 & 31) * 4;                                      \
      rv[p] = *(const u16x4*)&VWT[(((size_t)b * 16 + h) * 64 + row) * 1024 +      \
                                  (kt_) * 128 + c4];                              \
    }                                                                             \
    _Pragma("unroll") for (int p = 0; p < 8; ++p)                                 \
        rcb[p] = *(const u16x4*)&CB[cb_row + (kt_) * 128 + p * 16 + 4 * g];       \
  }

  LOAD_KV(0);
  f32x4 o_acc[4] = {};
  float l_par = 0.f;

  for (int kt = 0; kt < 8; ++kt) {
    __syncthreads();  // all waves done reading LDS of previous tile
#pragma unroll
    for (int p = 0; p < 8; ++p) {
      int i4 = p * 256 + t;
      int row = i4 >> 4, c4 = (i4 & 15) * 4;
      *(u16x4*)&lds_k[row * 72 + c4] = rk[p];
    }
#pragma unroll
    for (int p = 0; p < 8; ++p) {
      int i4 = p * 256 + t;
      int row = i4 >> 5, c4 = (i4 & 31) * 4;
      *(u16x4*)&lds_vt[row * 136 + c4] = rv[p];
    }
    // S^T init from CB (C-layout: row k = fm*16+4g+r, col j = ln)
    f32x4 s[8];
#pragma unroll
    for (int fm = 0; fm < 8; ++fm) {
#pragma unroll
      for (int r = 0; r < 4; ++r) s[fm][r] = bf2f(rcb[fm][r]);
    }
    if (kt < 7) LOAD_KV(kt + 1);  // prefetch next tile into regs (T14)
    __syncthreads();
    // S^T += K x Q
#pragma unroll
    for (int ks = 0; ks < 2; ++ks) {
#pragma unroll
      for (int fm = 0; fm < 8; ++fm) {
        short8 af = *(const short8*)&lds_k[(fm * 16 + ln) * 72 + ks * 32 + 8 * g];
        s[fm] = MFMA16(af, qf[ks], s[fm]);
      }
    }
    // P = 2^(s - 17)  (fixed shift; exact softmax after normalization)
#pragma unroll
    for (int fm = 0; fm < 8; ++fm) {
      float pv0 = fexp2(s[fm][0] - 17.0f);
      float pv1 = fexp2(s[fm][1] - 17.0f);
      float pv2 = fexp2(s[fm][2] - 17.0f);
      float pv3 = fexp2(s[fm][3] - 17.0f);
      l_par += (pv0 + pv1) + (pv2 + pv3);
      union { u16x4 v; unsigned u[2]; } pp;
      pp.u[0] = pk2(pv0, pv1);
      pp.u[1] = pk2(pv2, pv3);
      *(u16x4*)&pw[ln * 136 + fm * 16 + 4 * g] = pp.v;  // P^T -> [j=ln][k]
    }
    asm volatile("s_waitcnt lgkmcnt(0)" ::: "memory");
    // O^T += V^T x P^T
#pragma unroll
    for (int ks = 0; ks < 4; ++ks) {
      short8 bp = *(const short8*)&pw[ln * 136 + ks * 32 + 8 * g];
#pragma unroll
      for (int fm = 0; fm < 4; ++fm) {
        short8 av = *(const short8*)&lds_vt[(fm * 16 + ln) * 136 + ks * 32 + 8 * g];
        o_acc[fm] = MFMA16(av, bp, o_acc[fm]);
      }
    }
  }
  // row-sum: lanes with same ln (xor 16, 32) hold the 4 k-quarters of row j
  l_par += __shfl_xor(l_par, 16);
  l_par += __shfl_xor(l_par, 32);
  float inv = 1.0f / l_par;
  const size_t orow = ((size_t)b * 1024 + (j0 + w * 16 + ln)) * 1024 + h * 64;
#pragma unroll
  for (int fm = 0; fm < 4; ++fm) {
    union { u16x4 v; unsigned u[2]; } uo;
    uo.u[0] = pk2(o_acc[fm][0] * inv, o_acc[fm][1] * inv);
    uo.u[1] = pk2(o_acc[fm][2] * inv, o_acc[fm][3] * inv);
    *(u16x4*)&OB[orow + fm * 16 + 4 * g] = uo.v;  // d = fm*16+4g+r
  }
#undef LOAD_KV
}

// ---------------------------------------------------------------------------
extern "C" void kernel_launch(void* const* d_in, const int* in_sizes, int n_in,
                              void* d_out, int out_size, void* d_ws, size_t ws_size,
                              hipStream_t stream) {
  const float* q  = (const float*)d_in[0];
  // d_in[1] = k  -- intentionally unused (reference projects K from v)
  const float* v  = (const float*)d_in[2];
  const float* pb = (const float*)d_in[3];
  const float* Wq = (const float*)d_in[4];
  const float* Wk = (const float*)d_in[5];
  const float* Wv = (const float*)d_in[6];
  const float* Wo = (const float*)d_in[7];
  const float* bq = (const float*)d_in[8];
  const float* bk = (const float*)d_in[9];
  const float* bv = (const float*)d_in[10];
  const float* bo = (const float*)d_in[11];
  const int* qm = (const int*)d_in[12];
  const int* vm = (const int*)d_in[13];
  float* out = (float*)d_out;

  unsigned short* ws = (unsigned short*)d_ws;
  const size_t M1 = 1024 * 1024;
  unsigned short* WTQ = ws;
  unsigned short* WTK = WTQ + M1;
  unsigned short* WTV = WTK + M1;
  unsigned short* WTO = WTV + M1;
  unsigned short* QB  = WTO + M1;              // [8192][1024] bf16(q)
  unsigned short* VB  = QB + 8 * M1;           // [8192][1024] bf16(v)
  unsigned short* QW  = VB + 8 * M1;           // [8192][1024], scaled log2e/8
  unsigned short* KW  = QW + 8 * M1;
  unsigned short* VWT = KW + 8 * M1;           // [b][h][d][s]
  unsigned short* OB  = VWT + 8 * M1;
  unsigned short* CB  = OB + 8 * M1;           // [bh 128][jl 512][k 1024] stripe (134MB)

  k_wconv4<<<dim3(16, 16, 4), 256, 0, stream>>>(Wq, Wk, Wv, Wo, WTQ, WTK, WTV, WTO);
  k_cvt<<<dim3(4096, 2), 256, 0, stream>>>(q, v, QB, VB);
  k_proj3<<<dim3(8, 64, 3), 256, 0, stream>>>(QB, VB, WTQ, WTK, WTV, bq, bk, bv,
                                              QW, KW, VWT);
  for (int st = 0; st < 2; ++st) {
    k_pbias<<<dim3(8, 512), 256, 0, stream>>>(QW, pb, vm, CB, st * 512);
    k_attn<<<dim3(1024), 256, 0, stream>>>(QW, KW, VWT, CB, OB, st * 512);
  }
  k_out3<<<dim3(8, 64), 256, 0, stream>>>(OB, WTO, bo, qm, out);
}